// Round 2
// baseline (10160.352 us; speedup 1.0000x reference)
//
#include <hip/hip_runtime.h>
#include <cstddef>

#define SPATIAL (64*64*64)   // 262144 = 1<<18

// ---------------- Stats layout (floats, in ws) ----------------
// accumulators (zeroed each launch):
// 0   : gn_sum[8]     (b*4+g)
// 8   : gn_sumsq[8]
// 16  : in2_sum[16]   (b*8+o)
// 32  : in2_sumsq[16]
// 48  : in3_sum[64]   (b*32+o)
// 112 : in3_sumsq[64]
// derived:
// 176 : gn_a[64]      (b*32+c)
// 240 : gn_shift[64]
// 304 : in2_mu[16]
// 320 : in2_rs[16]
// 336 : in3_mu[64]
// 400 : in3_rs[64]

__device__ __forceinline__ float wave_reduce(float v) {
    #pragma unroll
    for (int off = 32; off; off >>= 1) v += __shfl_down(v, off);
    return v;
}

__global__ void zero_stats(float* __restrict__ stats) {
    if (threadIdx.x < 176) stats[threadIdx.x] = 0.0f;
}

// K1: depthwise conv (k = 3/5/7/9 per channel group) + bias + residual -> y1 (stored in d_out), GN sums
__global__ __launch_bounds__(256) void dwconv_kernel(
    const float* __restrict__ x,
    const float* __restrict__ w3, const float* __restrict__ b3,
    const float* __restrict__ w5, const float* __restrict__ b5,
    const float* __restrict__ w7, const float* __restrict__ b7,
    const float* __restrict__ w9, const float* __restrict__ b9,
    float* __restrict__ y1, float* __restrict__ stats)
{
    const int bc = blockIdx.y;           // b*32 + c
    const int b  = bc >> 5;
    const int c  = bc & 31;
    const int g  = c >> 3;
    const int cl = c & 7;
    const int k  = 3 + 2 * g;
    const int p  = k >> 1;
    const int k3 = k * k * k;

    const float* wsrc = (g == 0 ? w3 : g == 1 ? w5 : g == 2 ? w7 : w9) + cl * k3;
    const float* bsrc = (g == 0 ? b3 : g == 1 ? b5 : g == 2 ? b7 : b9);

    __shared__ float wl[729];
    for (int i = threadIdx.x; i < k3; i += 256) wl[i] = wsrc[i];
    __syncthreads();

    const float bias = bsrc[cl];
    const int s = blockIdx.x * 256 + threadIdx.x;
    const int d = s >> 12, h = (s >> 6) & 63, w = s & 63;
    const float* xin = x + ((size_t)bc << 18);

    float acc = bias;
    int idx = 0;
    for (int kd = 0; kd < k; kd++) {
        const int zd = d + kd - p;
        const bool okd = (unsigned)zd < 64u;
        for (int kh = 0; kh < k; kh++) {
            const int zh = h + kh - p;
            const bool ok = okd && ((unsigned)zh < 64u);
            const int rb = (zd << 12) + (zh << 6);
            for (int kw = 0; kw < k; kw++, idx++) {
                const int zw = w + kw - p;
                if (ok && (unsigned)zw < 64u)
                    acc += xin[rb + zw] * wl[idx];
            }
        }
    }
    const float val = acc + xin[s];
    y1[((size_t)bc << 18) + s] = val;

    float sm = wave_reduce(val);
    float sq = wave_reduce(val * val);
    if ((threadIdx.x & 63) == 0) {
        atomicAdd(&stats[b * 4 + g], sm);
        atomicAdd(&stats[8 + b * 4 + g], sq);
    }
}

// K2: GN finalize -> per-(b,c) affine a, shift
__global__ void gn_finalize(const float* __restrict__ gn_w, const float* __restrict__ gn_b,
                            float* __restrict__ stats)
{
    const int i = threadIdx.x;
    if (i >= 64) return;
    const int b = i >> 5, c = i & 31, g = c >> 3;
    const float N = 8.0f * (float)SPATIAL;  // 2097152
    const float mu  = stats[b * 4 + g] / N;
    const float var = stats[8 + b * 4 + g] / N - mu * mu;
    const float rs  = rsqrtf(var + 1e-5f);
    const float a   = gn_w[c] * rs;
    stats[176 + i] = a;
    stats[240 + i] = gn_b[c] - mu * a;
}

// K3: GN affine + exact GELU + 1x1x1 conv (32->8) -> t (fp32 ws), IN2 sums
__global__ __launch_bounds__(256) void pw_kernel(
    const float* __restrict__ y1, const float* __restrict__ w_pw,
    float* __restrict__ t, float* __restrict__ stats)
{
    const int b = blockIdx.y;
    const int s = blockIdx.x * 256 + threadIdx.x;

    __shared__ float wl[256], ga[32], gsh[32];
    wl[threadIdx.x] = w_pw[threadIdx.x];
    if (threadIdx.x < 32) {
        ga[threadIdx.x]  = stats[176 + b * 32 + threadIdx.x];
        gsh[threadIdx.x] = stats[240 + b * 32 + threadIdx.x];
    }
    __syncthreads();

    float acc[8];
    #pragma unroll
    for (int o = 0; o < 8; o++) acc[o] = 0.0f;

    const float* yb = y1 + ((size_t)b << 23);   // b * 32 * SPATIAL
    for (int c = 0; c < 32; c++) {
        float v = yb[((size_t)c << 18) + s];
        v = ga[c] * v + gsh[c];
        const float ge = 0.5f * v * (1.0f + erff(v * 0.70710678118654752f));
        #pragma unroll
        for (int o = 0; o < 8; o++) acc[o] += ge * wl[o * 32 + c];
    }

    float* tb = t + ((size_t)b << 21);          // b * 8 * SPATIAL
    #pragma unroll
    for (int o = 0; o < 8; o++) {
        tb[((size_t)o << 18) + s] = acc[o];
        float sm = wave_reduce(acc[o]);
        float sq = wave_reduce(acc[o] * acc[o]);
        if ((threadIdx.x & 63) == 0) {
            atomicAdd(&stats[16 + b * 8 + o], sm);
            atomicAdd(&stats[32 + b * 8 + o], sq);
        }
    }
}

// K4: IN2 finalize
__global__ void in2_finalize(float* __restrict__ stats)
{
    const int i = threadIdx.x;
    if (i >= 16) return;
    const float N = (float)SPATIAL;
    const float mu  = stats[16 + i] / N;
    const float var = stats[32 + i] / N - mu * mu;
    stats[304 + i] = mu;
    stats[320 + i] = rsqrtf(var + 1e-5f);
}

// K5: apply IN2 + SiLU -> u (fp32 ws)
__global__ __launch_bounds__(256) void insilu_kernel(
    const float* __restrict__ t, float* __restrict__ u, const float* __restrict__ stats)
{
    const int i = blockIdx.x * 256 + threadIdx.x;    // 4194304 total
    const int bo = i >> 18;                           // b*8+o
    const float v = (t[i] - stats[304 + bo]) * stats[320 + bo];
    u[i] = v / (1.0f + expf(-v));
}

// K6: 3x3x3 conv (8->32) -> writes d_out (overwrites y1, which is dead), IN3 sums
__global__ __launch_bounds__(256) void conv3_kernel(
    const float* __restrict__ u, const float* __restrict__ w_nxn,
    float* __restrict__ vout, float* __restrict__ stats)
{
    const int bo = blockIdx.y;    // b*32 + o
    const int b = bo >> 5, o = bo & 31;

    __shared__ float wl[216];
    for (int i = threadIdx.x; i < 216; i += 256) wl[i] = w_nxn[o * 216 + i];
    __syncthreads();

    const int s = blockIdx.x * 256 + threadIdx.x;
    const int d = s >> 12, h = (s >> 6) & 63, w = s & 63;
    const float* ub = u + ((size_t)b << 21);

    float acc = 0.0f;
    for (int c = 0; c < 8; c++) {
        const float* uc = ub + ((size_t)c << 18);
        const float* wc = wl + c * 27;
        int idx = 0;
        #pragma unroll
        for (int kd = 0; kd < 3; kd++) {
            const int zd = d + kd - 1;
            const bool okd = (unsigned)zd < 64u;
            #pragma unroll
            for (int kh = 0; kh < 3; kh++) {
                const int zh = h + kh - 1;
                const bool ok = okd && ((unsigned)zh < 64u);
                const int rb = (zd << 12) + (zh << 6);
                #pragma unroll
                for (int kw = 0; kw < 3; kw++, idx++) {
                    const int zw = w + kw - 1;
                    if (ok && (unsigned)zw < 64u) acc += uc[rb + zw] * wc[idx];
                }
            }
        }
    }
    vout[((size_t)bo << 18) + s] = acc;

    float sm = wave_reduce(acc);
    float sq = wave_reduce(acc * acc);
    if ((threadIdx.x & 63) == 0) {
        atomicAdd(&stats[48 + bo], sm);
        atomicAdd(&stats[112 + bo], sq);
    }
}

// K7: IN3 finalize
__global__ void in3_finalize(float* __restrict__ stats)
{
    const int i = threadIdx.x;
    if (i >= 64) return;
    const float N = (float)SPATIAL;
    const float mu  = stats[48 + i] / N;
    const float var = stats[112 + i] / N - mu * mu;
    stats[336 + i] = mu;
    stats[400 + i] = rsqrtf(var + 1e-5f);
}

// K8: IN3 + SiLU + residual x, in place on d_out
__global__ __launch_bounds__(256) void final_kernel(
    const float* __restrict__ x, float* __restrict__ out, const float* __restrict__ stats)
{
    const int i = blockIdx.x * 256 + threadIdx.x;    // 16777216 total
    const int bc = i >> 18;                           // b*32 + c
    float v = (out[i] - stats[336 + bc]) * stats[400 + bc];
    v = v / (1.0f + expf(-v));
    out[i] = v + x[i];
}

extern "C" void kernel_launch(void* const* d_in, const int* in_sizes, int n_in,
                              void* d_out, int out_size, void* d_ws, size_t ws_size,
                              hipStream_t stream)
{
    const float* x    = (const float*)d_in[0];
    const float* w3   = (const float*)d_in[1];
    const float* b3   = (const float*)d_in[2];
    const float* w5   = (const float*)d_in[3];
    const float* b5   = (const float*)d_in[4];
    const float* w7   = (const float*)d_in[5];
    const float* b7   = (const float*)d_in[6];
    const float* w9   = (const float*)d_in[7];
    const float* b9   = (const float*)d_in[8];
    const float* gn_w = (const float*)d_in[9];
    const float* gn_b = (const float*)d_in[10];
    const float* w_pw = (const float*)d_in[11];
    const float* w_nxn= (const float*)d_in[12];

    char* ws = (char*)d_ws;
    float* t     = (float*)ws;                         // 16,777,216 B (2*8*SPATIAL fp32)
    float* u     = (float*)(ws + 16777216);            // 16,777,216 B
    float* stats = (float*)(ws + 33554432);            // 464 floats

    float* out = (float*)d_out;                        // also doubles as y1 scratch

    zero_stats<<<1, 256, 0, stream>>>(stats);
    dwconv_kernel<<<dim3(1024, 64), 256, 0, stream>>>(x, w3, b3, w5, b5, w7, b7, w9, b9, out, stats);
    gn_finalize<<<1, 64, 0, stream>>>(gn_w, gn_b, stats);
    pw_kernel<<<dim3(1024, 2), 256, 0, stream>>>(out, w_pw, t, stats);
    in2_finalize<<<1, 16, 0, stream>>>(stats);
    insilu_kernel<<<16384, 256, 0, stream>>>(t, u, stats);
    conv3_kernel<<<dim3(1024, 64), 256, 0, stream>>>(u, w_nxn, out, stats);
    in3_finalize<<<1, 64, 0, stream>>>(stats);
    final_kernel<<<65536, 256, 0, stream>>>(x, out, stats);
}

// Round 3
// 1218.434 us; speedup vs baseline: 8.3389x; 8.3389x over previous
//
#include <hip/hip_runtime.h>
#include <cstddef>

#define SPATIAL (64*64*64)   // 262144 = 1<<18

// ---------------- Stats layout (floats, in ws) ----------------
// accumulators (zeroed each launch):
// 0   : gn_sum[8]     (b*4+g)
// 8   : gn_sumsq[8]
// 16  : in2_sum[16]   (b*8+o)
// 32  : in2_sumsq[16]
// 48  : in3_sum[64]   (b*32+o)
// 112 : in3_sumsq[64]
// derived:
// 176 : gn_a[64]      (b*32+c)
// 240 : gn_shift[64]
// 304 : in2_mu[16]
// 320 : in2_rs[16]
// 336 : in3_mu[64]
// 400 : in3_rs[64]

__device__ __forceinline__ float wave_reduce(float v) {
    #pragma unroll
    for (int off = 32; off; off >>= 1) v += __shfl_down(v, off);
    return v;
}

__global__ void zero_stats(float* __restrict__ stats) {
    if (threadIdx.x < 176) stats[threadIdx.x] = 0.0f;
}

// ================= K1: depthwise conv, LDS ring-buffer version =================
// Block tile: one (b,c) plane, 16 h-rows, 16 d-slices, full w.
// LDS: ring of 9 slices, each 24 rows x 72 cols (4-col pad left/right for
// float4-aligned sliding windows; zero-filled halo).

__device__ __forceinline__ void dw_stage(const float* __restrict__ xin,
                                         float* __restrict__ ring, int zd, int h0) {
    float* dst = ring + ((zd + 36) % 9) * 1728;
    const float* src = xin + ((size_t)zd << 12);
    const bool dok = (unsigned)zd < 64u;
    for (int i = threadIdx.x; i < 1728; i += 256) {
        const int row = i / 72;
        const int col = i - row * 72;
        const int zh = h0 - 4 + row;
        const int zw = col - 4;
        float v = 0.0f;
        if (dok & ((unsigned)zh < 64u) & ((unsigned)zw < 64u)) v = src[(zh << 6) + zw];
        dst[i] = v;
    }
}

template<int K>
__device__ __forceinline__ void dw_impl(const float* __restrict__ x,
                                        const float* __restrict__ wsrc, float bias,
                                        int bc, int h0, int d0,
                                        float* __restrict__ ring,
                                        float* __restrict__ stats, int b,
                                        float* __restrict__ y1)
{
    constexpr int P = K / 2;
    constexpr int G = P - 1;                 // group index 0..3
    const float* xin = x + ((size_t)bc << 18);

    for (int zd = d0 - P; zd < d0 + P; ++zd) dw_stage(xin, ring, zd, h0);

    const int r  = threadIdx.x >> 4;         // 0..15 output row
    const int w0 = (threadIdx.x & 15) << 2;  // 0..60 output col (x4)
    float gsum = 0.0f, gsq = 0.0f;

    for (int d = d0; d < d0 + 16; ++d) {
        dw_stage(xin, ring, d + P, h0);
        __syncthreads();

        float a0 = bias, a1 = bias, a2 = bias, a3 = bias;
        for (int kd = 0; kd < K; ++kd) {
            const float* sl = ring + ((d + kd - P + 36) % 9) * 1728;
            const float* wrow0 = wsrc + kd * K * K;    // wave-uniform -> s_load
            #pragma unroll
            for (int kh = 0; kh < K; ++kh) {
                const float* rowp = sl + (r + kh + (4 - P)) * 72 + w0;
                const float4 A  = *(const float4*)rowp;
                const float4 B4 = *(const float4*)(rowp + 4);
                const float4 C4 = *(const float4*)(rowp + 8);
                const float win[12] = {A.x,A.y,A.z,A.w, B4.x,B4.y,B4.z,B4.w,
                                       C4.x,C4.y,C4.z,C4.w};
                const float* wr = wrow0 + kh * K;
                #pragma unroll
                for (int kw = 0; kw < K; ++kw) {
                    const float wt = wr[kw];
                    a0 += win[kw + 4 - P] * wt;
                    a1 += win[kw + 5 - P] * wt;
                    a2 += win[kw + 6 - P] * wt;
                    a3 += win[kw + 7 - P] * wt;
                }
            }
        }
        // residual: center x values from LDS
        const float* cen = ring + ((d + 36) % 9) * 1728 + (r + 4) * 72 + (w0 + 4);
        const float4 xc = *(const float4*)cen;
        a0 += xc.x; a1 += xc.y; a2 += xc.z; a3 += xc.w;

        *(float4*)(y1 + ((size_t)bc << 18) + ((size_t)d << 12) +
                   ((size_t)(h0 + r) << 6) + w0) = make_float4(a0, a1, a2, a3);
        gsum += a0 + a1 + a2 + a3;
        gsq  += a0*a0 + a1*a1 + a2*a2 + a3*a3;
        __syncthreads();   // protect oldest ring slot before next stage
    }

    gsum = wave_reduce(gsum);
    gsq  = wave_reduce(gsq);
    if ((threadIdx.x & 63) == 0) {
        atomicAdd(&stats[b * 4 + G], gsum);
        atomicAdd(&stats[8 + b * 4 + G], gsq);
    }
}

__global__ __launch_bounds__(256) void dwconv_kernel(
    const float* __restrict__ x,
    const float* __restrict__ w3, const float* __restrict__ b3,
    const float* __restrict__ w5, const float* __restrict__ b5,
    const float* __restrict__ w7, const float* __restrict__ b7,
    const float* __restrict__ w9, const float* __restrict__ b9,
    float* __restrict__ y1, float* __restrict__ stats)
{
    __shared__ float ring[9 * 1728];   // 62208 B
    const int gid = blockIdx.x;        // 1024 blocks, k=9 group first
    const int g   = 3 - (gid >> 8);
    const int rr  = gid & 255;
    const int plane = rr >> 4;         // 0..15 = b*8 + cl
    const int hq  = (rr >> 2) & 3;
    const int dc  = rr & 3;
    const int b   = plane >> 3, cl = plane & 7;
    const int bc  = (b << 5) + (g << 3) + cl;
    const int h0  = hq << 4, d0 = dc << 4;

    switch (g) {
        case 0: dw_impl<3>(x, w3 + cl * 27,  b3[cl], bc, h0, d0, ring, stats, b, y1); break;
        case 1: dw_impl<5>(x, w5 + cl * 125, b5[cl], bc, h0, d0, ring, stats, b, y1); break;
        case 2: dw_impl<7>(x, w7 + cl * 343, b7[cl], bc, h0, d0, ring, stats, b, y1); break;
        default: dw_impl<9>(x, w9 + cl * 729, b9[cl], bc, h0, d0, ring, stats, b, y1); break;
    }
}

// K2: GN finalize -> per-(b,c) affine a, shift
__global__ void gn_finalize(const float* __restrict__ gn_w, const float* __restrict__ gn_b,
                            float* __restrict__ stats)
{
    const int i = threadIdx.x;
    if (i >= 64) return;
    const int b = i >> 5, c = i & 31, g = c >> 3;
    const float N = 8.0f * (float)SPATIAL;
    const float mu  = stats[b * 4 + g] / N;
    const float var = stats[8 + b * 4 + g] / N - mu * mu;
    const float rs  = rsqrtf(var + 1e-5f);
    const float a   = gn_w[c] * rs;
    stats[176 + i] = a;
    stats[240 + i] = gn_b[c] - mu * a;
}

// ============ K3: GN affine + exact GELU + 1x1x1 conv (32->8), float4 ============
__global__ __launch_bounds__(256) void pw_kernel(
    const float* __restrict__ y1, const float* __restrict__ w_pw,
    float* __restrict__ t, float* __restrict__ stats)
{
    const int bid = blockIdx.x;          // 512 blocks
    const int b   = bid >> 8;
    const int s0  = ((bid & 255) * 256 + threadIdx.x) * 4;  // wrong stride? see below
    // NOTE: each block covers 1024 spatial elems: recompute properly:
    // s0 = (bid&255)*1024 + tid*4
    const int s   = (bid & 255) * 1024 + threadIdx.x * 4;
    (void)s0;

    const float* yb = y1 + ((size_t)b << 23);
    float acc[8][4] = {};

    for (int c = 0; c < 32; ++c) {
        const float ga = stats[176 + b * 32 + c];   // uniform -> s_load
        const float gs = stats[240 + b * 32 + c];
        const float4 y = *(const float4*)(yb + ((size_t)c << 18) + s);
        float v0 = ga * y.x + gs, v1 = ga * y.y + gs, v2 = ga * y.z + gs, v3 = ga * y.w + gs;
        const float e0 = 0.5f * v0 * (1.0f + erff(v0 * 0.70710678118654752f));
        const float e1 = 0.5f * v1 * (1.0f + erff(v1 * 0.70710678118654752f));
        const float e2 = 0.5f * v2 * (1.0f + erff(v2 * 0.70710678118654752f));
        const float e3 = 0.5f * v3 * (1.0f + erff(v3 * 0.70710678118654752f));
        #pragma unroll
        for (int o = 0; o < 8; ++o) {
            const float wt = w_pw[o * 32 + c];      // uniform -> s_load
            acc[o][0] += e0 * wt; acc[o][1] += e1 * wt;
            acc[o][2] += e2 * wt; acc[o][3] += e3 * wt;
        }
    }

    float* tb = t + ((size_t)b << 21);
    #pragma unroll
    for (int o = 0; o < 8; ++o) {
        *(float4*)(tb + ((size_t)o << 18) + s) =
            make_float4(acc[o][0], acc[o][1], acc[o][2], acc[o][3]);
        float sm = acc[o][0] + acc[o][1] + acc[o][2] + acc[o][3];
        float sq = acc[o][0]*acc[o][0] + acc[o][1]*acc[o][1] +
                   acc[o][2]*acc[o][2] + acc[o][3]*acc[o][3];
        sm = wave_reduce(sm);
        sq = wave_reduce(sq);
        if ((threadIdx.x & 63) == 0) {
            atomicAdd(&stats[16 + b * 8 + o], sm);
            atomicAdd(&stats[32 + b * 8 + o], sq);
        }
    }
}

// K4: IN2 finalize
__global__ void in2_finalize(float* __restrict__ stats)
{
    const int i = threadIdx.x;
    if (i >= 16) return;
    const float N = (float)SPATIAL;
    const float mu  = stats[16 + i] / N;
    const float var = stats[32 + i] / N - mu * mu;
    stats[304 + i] = mu;
    stats[320 + i] = rsqrtf(var + 1e-5f);
}

// ===== K6: 3x3x3 conv (8->32), IN2+SiLU fused into LDS staging, ring over d =====
// Block tile: b, 8 d, 8 h-rows, 32 w. LDS: 8 ch x 3 slices x 10 rows x 40 cols.
__device__ __forceinline__ void c3_stage(const float* __restrict__ tb,
                                         float* __restrict__ ls,
                                         const float* __restrict__ stats,
                                         int b, int zd, int h0, int w0g)
{
    const bool dok = (unsigned)zd < 64u;
    const int slot = (zd + 33) % 3;
    for (int i = threadIdx.x; i < 3200; i += 256) {
        const int c   = i / 400;
        const int rem = i - c * 400;
        const int row = rem / 40;
        const int col = rem - row * 40;
        const int zh  = h0 - 1 + row;
        const int zw  = w0g + col - 4;
        float v = 0.0f;
        if (dok & ((unsigned)zh < 64u) & ((unsigned)zw < 64u)) {
            const float raw = tb[((size_t)c << 18) + ((size_t)zd << 12) + (zh << 6) + zw];
            const float mu = stats[304 + (b << 3) + c];
            const float rs = stats[320 + (b << 3) + c];
            const float xn = (raw - mu) * rs;
            v = xn / (1.0f + expf(-xn));
        }
        ls[c * 1200 + slot * 400 + row * 40 + col] = v;
    }
}

__global__ __launch_bounds__(256) void conv3_kernel(
    const float* __restrict__ t, const float* __restrict__ w_nxn,
    float* __restrict__ out, float* __restrict__ stats)
{
    __shared__ float ls[9600];            // 38400 B
    const int bid = blockIdx.x;           // 256 blocks
    const int b   = bid >> 7;
    const int r7  = bid & 127;
    const int d0  = (r7 >> 4) << 3;       // 8 d-chunks
    const int h0  = ((r7 >> 1) & 7) << 3; // 8 h-chunks
    const int w0g = (r7 & 1) << 5;        // 2 w-chunks

    const int tid = threadIdx.x;
    const int w0  = (tid & 7) << 2;       // 0..28
    const int r   = (tid >> 3) & 7;       // 0..7
    const int oq  = __builtin_amdgcn_readfirstlane(tid >> 6);  // wave-uniform
    const int o0  = oq << 3;

    const float* tb = t + ((size_t)b << 21);
    float s3[8] = {}, q3[8] = {};

    c3_stage(tb, ls, stats, b, d0 - 1, h0, w0g);
    c3_stage(tb, ls, stats, b, d0,     h0, w0g);

    for (int d = d0; d < d0 + 8; ++d) {
        c3_stage(tb, ls, stats, b, d + 1, h0, w0g);
        __syncthreads();

        float acc[8][4] = {};
        for (int c = 0; c < 8; ++c) {
            const float* lc = ls + c * 1200;
            const float* wc = w_nxn + c * 27;
            #pragma unroll
            for (int kd = 0; kd < 3; ++kd) {
                const float* sl = lc + ((d + kd + 32) % 3) * 400;  // zd = d+kd-1
                #pragma unroll
                for (int kh = 0; kh < 3; ++kh) {
                    const float* rowp = sl + (r + kh) * 40 + w0;
                    const float4 A  = *(const float4*)rowp;
                    const float4 B4 = *(const float4*)(rowp + 4);
                    const float4 C4 = *(const float4*)(rowp + 8);
                    const float win[12] = {A.x,A.y,A.z,A.w, B4.x,B4.y,B4.z,B4.w,
                                           C4.x,C4.y,C4.z,C4.w};
                    #pragma unroll
                    for (int oi = 0; oi < 8; ++oi) {
                        const float* wp = wc + (o0 + oi) * 216 + kd * 9 + kh * 3; // uniform
                        #pragma unroll
                        for (int kw = 0; kw < 3; ++kw) {
                            const float wt = wp[kw];
                            acc[oi][0] += win[kw + 3] * wt;
                            acc[oi][1] += win[kw + 4] * wt;
                            acc[oi][2] += win[kw + 5] * wt;
                            acc[oi][3] += win[kw + 6] * wt;
                        }
                    }
                }
            }
        }

        #pragma unroll
        for (int oi = 0; oi < 8; ++oi) {
            const int o = o0 + oi;
            *(float4*)(out + ((size_t)((b << 5) + o) << 18) + ((size_t)d << 12) +
                       ((size_t)(h0 + r) << 6) + (w0g + w0)) =
                make_float4(acc[oi][0], acc[oi][1], acc[oi][2], acc[oi][3]);
            s3[oi] += acc[oi][0] + acc[oi][1] + acc[oi][2] + acc[oi][3];
            q3[oi] += acc[oi][0]*acc[oi][0] + acc[oi][1]*acc[oi][1] +
                      acc[oi][2]*acc[oi][2] + acc[oi][3]*acc[oi][3];
        }
        __syncthreads();
    }

    #pragma unroll
    for (int oi = 0; oi < 8; ++oi) {
        float sm = wave_reduce(s3[oi]);
        float sq = wave_reduce(q3[oi]);
        if ((tid & 63) == 0) {
            atomicAdd(&stats[48 + (b << 5) + o0 + oi], sm);
            atomicAdd(&stats[112 + (b << 5) + o0 + oi], sq);
        }
    }
}

// K7: IN3 finalize
__global__ void in3_finalize(float* __restrict__ stats)
{
    const int i = threadIdx.x;
    if (i >= 64) return;
    const float N = (float)SPATIAL;
    const float mu  = stats[48 + i] / N;
    const float var = stats[112 + i] / N - mu * mu;
    stats[336 + i] = mu;
    stats[400 + i] = rsqrtf(var + 1e-5f);
}

// K8: IN3 + SiLU + residual x, in place on d_out (float4)
__global__ __launch_bounds__(256) void final_kernel(
    const float* __restrict__ x, float* __restrict__ out, const float* __restrict__ stats)
{
    const int idx = blockIdx.x * 256 + threadIdx.x;   // 4194304
    const size_t i4 = (size_t)idx << 2;
    const int bc = (int)(i4 >> 18);
    const float mu = stats[336 + bc], rs = stats[400 + bc];
    float4 v = *(const float4*)(out + i4);
    const float4 xr = *(const float4*)(x + i4);
    v.x = (v.x - mu) * rs; v.x = v.x / (1.0f + expf(-v.x)) + xr.x;
    v.y = (v.y - mu) * rs; v.y = v.y / (1.0f + expf(-v.y)) + xr.y;
    v.z = (v.z - mu) * rs; v.z = v.z / (1.0f + expf(-v.z)) + xr.z;
    v.w = (v.w - mu) * rs; v.w = v.w / (1.0f + expf(-v.w)) + xr.w;
    *(float4*)(out + i4) = v;
}

extern "C" void kernel_launch(void* const* d_in, const int* in_sizes, int n_in,
                              void* d_out, int out_size, void* d_ws, size_t ws_size,
                              hipStream_t stream)
{
    const float* x    = (const float*)d_in[0];
    const float* w3   = (const float*)d_in[1];
    const float* b3   = (const float*)d_in[2];
    const float* w5   = (const float*)d_in[3];
    const float* b5   = (const float*)d_in[4];
    const float* w7   = (const float*)d_in[5];
    const float* b7   = (const float*)d_in[6];
    const float* w9   = (const float*)d_in[7];
    const float* b9   = (const float*)d_in[8];
    const float* gn_w = (const float*)d_in[9];
    const float* gn_b = (const float*)d_in[10];
    const float* w_pw = (const float*)d_in[11];
    const float* w_nxn= (const float*)d_in[12];

    char* ws = (char*)d_ws;
    float* t     = (float*)ws;                // 16 MB (2*8*SPATIAL fp32)
    float* stats = (float*)(ws + 16777216);   // 464 floats

    float* out = (float*)d_out;               // y1 scratch, then conv3 output

    zero_stats<<<1, 256, 0, stream>>>(stats);
    dwconv_kernel<<<1024, 256, 0, stream>>>(x, w3, b3, w5, b5, w7, b7, w9, b9, out, stats);
    gn_finalize<<<1, 64, 0, stream>>>(gn_w, gn_b, stats);
    pw_kernel<<<512, 256, 0, stream>>>(out, w_pw, t, stats);
    in2_finalize<<<1, 16, 0, stream>>>(stats);
    conv3_kernel<<<256, 256, 0, stream>>>(t, w_nxn, out, stats);
    in3_finalize<<<1, 64, 0, stream>>>(stats);
    final_kernel<<<16384, 256, 0, stream>>>(x, out, stats);
}

// Round 4
// 1035.482 us; speedup vs baseline: 9.8122x; 1.1767x over previous
//
#include <hip/hip_runtime.h>
#include <cstddef>

#define SPATIAL (64*64*64)   // 262144 = 1<<18

// ---------------- Stats layout (floats, in ws) ----------------
// accumulators (zeroed each launch):
// 0   : gn_sum[8]     (b*4+g)
// 8   : gn_sumsq[8]
// 16  : in2_sum[16]   (b*8+o)
// 32  : in2_sumsq[16]
// 48  : in3_sum[64]   (b*32+o)
// 112 : in3_sumsq[64]
// derived:
// 176 : gn_a[64]      (b*32+c)
// 240 : gn_shift[64]
// 304 : in2_mu[16]
// 320 : in2_rs[16]
// 336 : in3_mu[64]
// 400 : in3_rs[64]

__device__ __forceinline__ float wave_reduce(float v) {
    #pragma unroll
    for (int off = 32; off; off >>= 1) v += __shfl_down(v, off);
    return v;
}

__global__ void zero_stats(float* __restrict__ stats) {
    if (threadIdx.x < 176) stats[threadIdx.x] = 0.0f;
}

// ================= K1: depthwise conv =================
// Tile per block: one (b,c) plane, h-tile 8, d-tile 16, full w (64).
// LDS ring: 12 slices x 16 rows x 73 cols (odd stride 73 -> conflict-free b32
// windows; halo 4 rows/cols zero-filled; fixed layout for all k).
// Threads: 256 = 4 waves; wave = one d of the current d-quad; lane = 8r x 8w;
// thread computes 8 consecutive w outputs.

#define DW_RS   73
#define DW_SLICE (16 * DW_RS)   // 1168 dwords
#define DW_RING 12

__device__ __forceinline__ void dw_stage(const float* __restrict__ xin,
                                         float* __restrict__ ring, int zd, int h0) {
    float* dst = ring + ((zd + 24) % DW_RING) * DW_SLICE;
    const float* src = xin + ((size_t)zd << 12);
    const bool dok = (unsigned)zd < 64u;
    for (int i = threadIdx.x; i < DW_SLICE; i += 256) {
        const int row = i / DW_RS;
        const int col = i - row * DW_RS;
        const int zh = h0 - 4 + row;
        const int zw = col - 4;
        float v = 0.0f;
        if (dok & ((unsigned)zh < 64u) & ((unsigned)zw < 64u)) v = src[(zh << 6) + zw];
        dst[i] = v;
    }
}

template<int K>
__device__ __forceinline__ void dw_impl(const float* __restrict__ x,
                                        const float* __restrict__ wsrc, float bias,
                                        int bc, int h0, int d0,
                                        float* __restrict__ ring,
                                        float* __restrict__ stats, int b,
                                        float* __restrict__ y1)
{
    constexpr int P = K / 2;
    constexpr int G = P - 1;          // group index 0..3
    constexpr int WIN = 8 + 2 * P;
    const float* xin = x + ((size_t)bc << 18);

    // initial slices: d0-P .. d0+P-1
    for (int zd = d0 - P; zd < d0 + P; ++zd) dw_stage(xin, ring, zd, h0);

    const int lane = threadIdx.x & 63;
    const int wave = threadIdx.x >> 6;          // 0..3 -> d offset in quad
    const int w0   = (lane & 7) << 3;           // 0,8,...,56
    const int r    = lane >> 3;                 // 0..7
    float gsum = 0.0f, gsq = 0.0f;

    for (int dq = d0; dq < d0 + 16; dq += 4) {
        #pragma unroll
        for (int j = 0; j < 4; ++j) dw_stage(xin, ring, dq + P + j, h0);
        __syncthreads();

        const int dd = dq + wave;
        float acc[8];
        #pragma unroll
        for (int i = 0; i < 8; ++i) acc[i] = bias;

        for (int kd = 0; kd < K; ++kd) {
            const float* sl = ring + ((dd + kd - P + 24) % DW_RING) * DW_SLICE;
            const float* wk = wsrc + kd * K * K;          // wave-uniform
            #pragma unroll
            for (int kh = 0; kh < K; ++kh) {
                const float* rowp = sl + (r + kh + 4 - P) * DW_RS + (w0 + 4 - P);
                float win[WIN];
                #pragma unroll
                for (int j = 0; j < WIN; ++j) win[j] = rowp[j];
                const float* wr = wk + kh * K;            // wave-uniform
                #pragma unroll
                for (int kw = 0; kw < K; ++kw) {
                    const float wt = wr[kw];
                    #pragma unroll
                    for (int i = 0; i < 8; ++i) acc[i] += win[kw + i] * wt;
                }
            }
        }
        // residual (center values of slice dd)
        const float* cen = ring + ((dd + 24) % DW_RING) * DW_SLICE + (r + 4) * DW_RS + (w0 + 4);
        #pragma unroll
        for (int i = 0; i < 8; ++i) acc[i] += cen[i];

        const size_t base = ((size_t)bc << 18) + ((size_t)dd << 12) +
                            ((size_t)(h0 + r) << 6) + w0;
        *(float4*)(y1 + base)     = make_float4(acc[0], acc[1], acc[2], acc[3]);
        *(float4*)(y1 + base + 4) = make_float4(acc[4], acc[5], acc[6], acc[7]);
        #pragma unroll
        for (int i = 0; i < 8; ++i) { gsum += acc[i]; gsq += acc[i] * acc[i]; }
        __syncthreads();
    }

    gsum = wave_reduce(gsum);
    gsq  = wave_reduce(gsq);
    if ((threadIdx.x & 63) == 0) {
        atomicAdd(&stats[b * 4 + G], gsum);
        atomicAdd(&stats[8 + b * 4 + G], gsq);
    }
}

__global__ __launch_bounds__(256) void dwconv_kernel(
    const float* __restrict__ x,
    const float* __restrict__ w3, const float* __restrict__ b3,
    const float* __restrict__ w5, const float* __restrict__ b5,
    const float* __restrict__ w7, const float* __restrict__ b7,
    const float* __restrict__ w9, const float* __restrict__ b9,
    float* __restrict__ y1, float* __restrict__ stats)
{
    __shared__ float ring[DW_RING * DW_SLICE];   // 56064 B -> 2 blocks/CU
    const int gid = blockIdx.x;                  // 2048 blocks, k=9 group first
    const int g   = 3 - (gid >> 9);
    const int rr  = gid & 511;
    const int plane = rr >> 5;                   // 0..15 = b*8 + cl
    const int hq  = (rr >> 2) & 7;               // 8 h-chunks of 8
    const int dc  = rr & 3;                      // 4 d-chunks of 16
    const int b   = plane >> 3, cl = plane & 7;
    const int bc  = (b << 5) + (g << 3) + cl;
    const int h0  = hq << 3, d0 = dc << 4;

    switch (g) {
        case 0: dw_impl<3>(x, w3 + cl * 27,  b3[cl], bc, h0, d0, ring, stats, b, y1); break;
        case 1: dw_impl<5>(x, w5 + cl * 125, b5[cl], bc, h0, d0, ring, stats, b, y1); break;
        case 2: dw_impl<7>(x, w7 + cl * 343, b7[cl], bc, h0, d0, ring, stats, b, y1); break;
        default: dw_impl<9>(x, w9 + cl * 729, b9[cl], bc, h0, d0, ring, stats, b, y1); break;
    }
}

// K2: GN finalize -> per-(b,c) affine a, shift
__global__ void gn_finalize(const float* __restrict__ gn_w, const float* __restrict__ gn_b,
                            float* __restrict__ stats)
{
    const int i = threadIdx.x;
    if (i >= 64) return;
    const int b = i >> 5, c = i & 31, g = c >> 3;
    const float N = 8.0f * (float)SPATIAL;
    const float mu  = stats[b * 4 + g] / N;
    const float var = stats[8 + b * 4 + g] / N - mu * mu;
    const float rs  = rsqrtf(var + 1e-5f);
    const float a   = gn_w[c] * rs;
    stats[176 + i] = a;
    stats[240 + i] = gn_b[c] - mu * a;
}

// ============ K3: GN affine + exact GELU + 1x1x1 conv (32->8), float4 ============
__global__ __launch_bounds__(256) void pw_kernel(
    const float* __restrict__ y1, const float* __restrict__ w_pw,
    float* __restrict__ t, float* __restrict__ stats)
{
    const int bid = blockIdx.x;                  // 512 blocks
    const int b   = bid >> 8;
    const int s   = (bid & 255) * 1024 + threadIdx.x * 4;

    const float* yb = y1 + ((size_t)b << 23);
    float acc[8][4] = {};

    for (int cc = 0; cc < 32; cc += 8) {
        float4 yv[8];
        #pragma unroll
        for (int u = 0; u < 8; ++u)
            yv[u] = *(const float4*)(yb + ((size_t)(cc + u) << 18) + s);
        #pragma unroll
        for (int u = 0; u < 8; ++u) {
            const int c = cc + u;
            const float ga = stats[176 + b * 32 + c];   // uniform -> s_load
            const float gs = stats[240 + b * 32 + c];
            float v0 = ga * yv[u].x + gs, v1 = ga * yv[u].y + gs;
            float v2 = ga * yv[u].z + gs, v3 = ga * yv[u].w + gs;
            const float e0 = 0.5f * v0 * (1.0f + erff(v0 * 0.70710678118654752f));
            const float e1 = 0.5f * v1 * (1.0f + erff(v1 * 0.70710678118654752f));
            const float e2 = 0.5f * v2 * (1.0f + erff(v2 * 0.70710678118654752f));
            const float e3 = 0.5f * v3 * (1.0f + erff(v3 * 0.70710678118654752f));
            #pragma unroll
            for (int o = 0; o < 8; ++o) {
                const float wt = w_pw[o * 32 + c];      // uniform -> s_load
                acc[o][0] += e0 * wt; acc[o][1] += e1 * wt;
                acc[o][2] += e2 * wt; acc[o][3] += e3 * wt;
            }
        }
    }

    float* tb = t + ((size_t)b << 21);
    #pragma unroll
    for (int o = 0; o < 8; ++o) {
        *(float4*)(tb + ((size_t)o << 18) + s) =
            make_float4(acc[o][0], acc[o][1], acc[o][2], acc[o][3]);
        float sm = acc[o][0] + acc[o][1] + acc[o][2] + acc[o][3];
        float sq = acc[o][0]*acc[o][0] + acc[o][1]*acc[o][1] +
                   acc[o][2]*acc[o][2] + acc[o][3]*acc[o][3];
        sm = wave_reduce(sm);
        sq = wave_reduce(sq);
        if ((threadIdx.x & 63) == 0) {
            atomicAdd(&stats[16 + b * 8 + o], sm);
            atomicAdd(&stats[32 + b * 8 + o], sq);
        }
    }
}

// K4: IN2 finalize
__global__ void in2_finalize(float* __restrict__ stats)
{
    const int i = threadIdx.x;
    if (i >= 16) return;
    const float N = (float)SPATIAL;
    const float mu  = stats[16 + i] / N;
    const float var = stats[32 + i] / N - mu * mu;
    stats[304 + i] = mu;
    stats[320 + i] = rsqrtf(var + 1e-5f);
}

// ===== K6: 3x3x3 conv (8->32), IN2+SiLU fused into staging, ring over d =====
// Tile: b, d-tile 4, h-tile 8, w-tile 32. LDS: 8c x 3 slices x 10 rows x 41 cols.
#define C3_RS 41
#define C3_ROWSZ (10 * C3_RS)    // 410
#define C3_CH (3 * C3_ROWSZ)     // 1230

__device__ __forceinline__ void c3_stage(const float* __restrict__ tb,
                                         float* __restrict__ ls,
                                         const float* __restrict__ stats,
                                         int b, int zd, int h0, int w0g)
{
    const bool dok = (unsigned)zd < 64u;
    const int slot = (zd + 33) % 3;
    for (int i = threadIdx.x; i < 8 * C3_ROWSZ; i += 256) {
        const int c   = i / C3_ROWSZ;
        const int rem = i - c * C3_ROWSZ;
        const int row = rem / C3_RS;
        const int col = rem - row * C3_RS;
        const int zh  = h0 - 1 + row;
        const int zw  = w0g + col - 4;
        float v = 0.0f;
        if (dok & ((unsigned)zh < 64u) & ((unsigned)zw < 64u)) {
            const float raw = tb[((size_t)c << 18) + ((size_t)zd << 12) + (zh << 6) + zw];
            const float mu = stats[304 + (b << 3) + c];
            const float rs = stats[320 + (b << 3) + c];
            const float xn = (raw - mu) * rs;
            v = xn / (1.0f + expf(-xn));
        }
        ls[c * C3_CH + slot * C3_ROWSZ + row * C3_RS + col] = v;
    }
}

__global__ __launch_bounds__(256) void conv3_kernel(
    const float* __restrict__ t, const float* __restrict__ w_nxn,
    float* __restrict__ out, float* __restrict__ stats)
{
    __shared__ float ls[8 * C3_CH];       // 39360 B -> 4 blocks/CU
    const int bid = blockIdx.x;           // 512 blocks
    const int b   = bid >> 8;
    const int r8  = bid & 255;
    const int d0  = (r8 >> 4) << 2;       // 16 d-chunks of 4
    const int h0  = ((r8 >> 1) & 7) << 3; // 8 h-chunks of 8
    const int w0g = (r8 & 1) << 5;        // 2 w-chunks of 32

    const int tid = threadIdx.x;
    const int w0  = (tid & 7) << 2;       // 0..28
    const int r   = (tid >> 3) & 7;       // 0..7
    const int oq  = __builtin_amdgcn_readfirstlane(tid >> 6);  // wave-uniform
    const int o0  = oq << 3;

    const float* tb = t + ((size_t)b << 21);
    float s3[8] = {}, q3[8] = {};

    c3_stage(tb, ls, stats, b, d0 - 1, h0, w0g);
    c3_stage(tb, ls, stats, b, d0,     h0, w0g);

    for (int d = d0; d < d0 + 4; ++d) {
        c3_stage(tb, ls, stats, b, d + 1, h0, w0g);
        __syncthreads();

        float acc[8][4] = {};
        for (int c = 0; c < 8; ++c) {
            const float* lc = ls + c * C3_CH;
            const float* wc = w_nxn + c * 27;
            #pragma unroll
            for (int kd = 0; kd < 3; ++kd) {
                const float* sl = lc + ((d + kd + 32) % 3) * C3_ROWSZ;  // zd = d+kd-1
                #pragma unroll
                for (int kh = 0; kh < 3; ++kh) {
                    const float* rowp = sl + (r + kh) * C3_RS + w0 + 3;
                    float win[6];
                    #pragma unroll
                    for (int j = 0; j < 6; ++j) win[j] = rowp[j];
                    #pragma unroll
                    for (int oi = 0; oi < 8; ++oi) {
                        const float* wp = wc + (o0 + oi) * 216 + kd * 9 + kh * 3; // uniform
                        #pragma unroll
                        for (int kw = 0; kw < 3; ++kw) {
                            const float wt = wp[kw];
                            acc[oi][0] += win[kw]     * wt;
                            acc[oi][1] += win[kw + 1] * wt;
                            acc[oi][2] += win[kw + 2] * wt;
                            acc[oi][3] += win[kw + 3] * wt;
                        }
                    }
                }
            }
        }

        #pragma unroll
        for (int oi = 0; oi < 8; ++oi) {
            const int o = o0 + oi;
            *(float4*)(out + ((size_t)((b << 5) + o) << 18) + ((size_t)d << 12) +
                       ((size_t)(h0 + r) << 6) + (w0g + w0)) =
                make_float4(acc[oi][0], acc[oi][1], acc[oi][2], acc[oi][3]);
            s3[oi] += acc[oi][0] + acc[oi][1] + acc[oi][2] + acc[oi][3];
            q3[oi] += acc[oi][0]*acc[oi][0] + acc[oi][1]*acc[oi][1] +
                      acc[oi][2]*acc[oi][2] + acc[oi][3]*acc[oi][3];
        }
        __syncthreads();
    }

    #pragma unroll
    for (int oi = 0; oi < 8; ++oi) {
        float sm = wave_reduce(s3[oi]);
        float sq = wave_reduce(q3[oi]);
        if ((tid & 63) == 0) {
            atomicAdd(&stats[48 + (b << 5) + o0 + oi], sm);
            atomicAdd(&stats[112 + (b << 5) + o0 + oi], sq);
        }
    }
}

// K7: IN3 finalize
__global__ void in3_finalize(float* __restrict__ stats)
{
    const int i = threadIdx.x;
    if (i >= 64) return;
    const float N = (float)SPATIAL;
    const float mu  = stats[48 + i] / N;
    const float var = stats[112 + i] / N - mu * mu;
    stats[336 + i] = mu;
    stats[400 + i] = rsqrtf(var + 1e-5f);
}

// K8: IN3 + SiLU + residual x, in place on d_out (float4)
__global__ __launch_bounds__(256) void final_kernel(
    const float* __restrict__ x, float* __restrict__ out, const float* __restrict__ stats)
{
    const int idx = blockIdx.x * 256 + threadIdx.x;   // 4194304
    const size_t i4 = (size_t)idx << 2;
    const int bc = (int)(i4 >> 18);
    const float mu = stats[336 + bc], rs = stats[400 + bc];
    float4 v = *(const float4*)(out + i4);
    const float4 xr = *(const float4*)(x + i4);
    v.x = (v.x - mu) * rs; v.x = v.x / (1.0f + expf(-v.x)) + xr.x;
    v.y = (v.y - mu) * rs; v.y = v.y / (1.0f + expf(-v.y)) + xr.y;
    v.z = (v.z - mu) * rs; v.z = v.z / (1.0f + expf(-v.z)) + xr.z;
    v.w = (v.w - mu) * rs; v.w = v.w / (1.0f + expf(-v.w)) + xr.w;
    *(float4*)(out + i4) = v;
}

extern "C" void kernel_launch(void* const* d_in, const int* in_sizes, int n_in,
                              void* d_out, int out_size, void* d_ws, size_t ws_size,
                              hipStream_t stream)
{
    const float* x    = (const float*)d_in[0];
    const float* w3   = (const float*)d_in[1];
    const float* b3   = (const float*)d_in[2];
    const float* w5   = (const float*)d_in[3];
    const float* b5   = (const float*)d_in[4];
    const float* w7   = (const float*)d_in[5];
    const float* b7   = (const float*)d_in[6];
    const float* w9   = (const float*)d_in[7];
    const float* b9   = (const float*)d_in[8];
    const float* gn_w = (const float*)d_in[9];
    const float* gn_b = (const float*)d_in[10];
    const float* w_pw = (const float*)d_in[11];
    const float* w_nxn= (const float*)d_in[12];

    char* ws = (char*)d_ws;
    float* t     = (float*)ws;                // 16 MB (2*8*SPATIAL fp32)
    float* stats = (float*)(ws + 16777216);   // 464 floats

    float* out = (float*)d_out;               // y1 scratch, then conv3 output

    zero_stats<<<1, 256, 0, stream>>>(stats);
    dwconv_kernel<<<2048, 256, 0, stream>>>(x, w3, b3, w5, b5, w7, b7, w9, b9, out, stats);
    gn_finalize<<<1, 64, 0, stream>>>(gn_w, gn_b, stats);
    pw_kernel<<<512, 256, 0, stream>>>(out, w_pw, t, stats);
    in2_finalize<<<1, 16, 0, stream>>>(stats);
    conv3_kernel<<<512, 256, 0, stream>>>(t, w_nxn, out, stats);
    in3_finalize<<<1, 64, 0, stream>>>(stats);
    final_kernel<<<16384, 256, 0, stream>>>(x, out, stats);
}